// Round 1
// baseline (189.641 us; speedup 1.0000x reference)
//
#include <hip/hip_runtime.h>
#include <hip/hip_bf16.h>

// ---------- types ----------
typedef __attribute__((ext_vector_type(8))) short short8;      // 8 x bf16 (4 VGPR) MFMA frag
typedef __attribute__((ext_vector_type(4))) float f32x4;       // MFMA accumulator
typedef __attribute__((ext_vector_type(4))) unsigned short u16x4;

// ---------- constants ----------
// B=4, N=1024, C=768, H=12, Dh=64, 3C=2304, scale=(C*H)^-0.5 = 1/96
#define NB 4
#define NN 1024
#define NC 768
#define NH 12
#define TC 2304

// workspace byte offsets
#define OFF_XB   0ul                       // x bf16          4096*768*2  = 6291456
#define OFF_WQ   6291456ul                 // qkv_w bf16      2304*768*2  = 3538944
#define OFF_WMU  (OFF_WQ + 3538944ul)      // mu_w bf16       768*384*2   = 589824
#define OFF_WLS  (OFF_WMU + 589824ul)      // ls_w bf16
#define OFF_QKVB (OFF_WLS + 589824ul)      // qkv bf16        4096*2304*2 = 18874368
#define OFF_VT   (OFF_QKVB + 18874368ul)   // v transposed    48*64*1024*2= 6291456
#define OFF_OUTB (OFF_VT + 6291456ul)      // attn-out bf16   4096*768*2  = 6291456

__device__ __forceinline__ unsigned short f2bf(float f) {
    unsigned int u = __float_as_uint(f);
    u = (u + 0x7FFFu + ((u >> 16) & 1u)) >> 16;
    return (unsigned short)u;
}

__device__ __forceinline__ void gload_lds16(const unsigned short* g, unsigned short* l) {
    __builtin_amdgcn_global_load_lds(
        (const __attribute__((address_space(1))) unsigned int*)g,
        (__attribute__((address_space(3))) unsigned int*)l, 16, 0, 0);
}

// ---------- cast f32 -> bf16 (vectorized) ----------
__global__ void cast_bf16(const float* __restrict__ in, unsigned short* __restrict__ out, int n4) {
    int i = blockIdx.x * blockDim.x + threadIdx.x;
    if (i < n4) {
        f32x4 v = ((const f32x4*)in)[i];
        u16x4 o;
#pragma unroll
        for (int j = 0; j < 4; ++j) o[j] = f2bf(v[j]);
        ((u16x4*)out)[i] = o;
    }
}

// ---------- generic NT bf16 GEMM: C(MxN) = A(MxK) * B(NxK)^T ----------
// 128x128 tile, BK=32, 4 waves each 64x64 (4x4 of 16x16x32 MFMA), global_load_lds staging.
// EPI=0: bf16 out, no bias.  EPI=1: f32 out + bias[col].
template <int EPI>
__global__ __launch_bounds__(256, 2) void gemm_nt(
    const unsigned short* __restrict__ A, const unsigned short* __restrict__ Bm,
    int K, int lda, int ldb, void* __restrict__ Cout, int ldc, const float* __restrict__ bias)
{
    __shared__ unsigned short As[128 * 32];
    __shared__ unsigned short Bs[128 * 32];
    const int t = threadIdx.x;
    const int lane = t & 63;
    const int wv = t >> 6;
    const int wm = wv >> 1, wn = wv & 1;
    const int li = lane & 15;
    const int koff = (lane >> 4) * 8;
    const int row0 = blockIdx.y * 128;
    const int col0 = blockIdx.x * 128;

    f32x4 acc[4][4] = {};

    const int tr = t >> 2;          // 0..63
    const int tc = (t & 3) * 8;     // 0,8,16,24
    const unsigned short* ag = A + (size_t)(row0 + tr) * lda + tc;
    const unsigned short* bg = Bm + (size_t)(col0 + tr) * ldb + tc;

    for (int kt = 0; kt < K; kt += 32) {
        gload_lds16(ag,            As + t * 8);
        gload_lds16(ag + 64 * lda, As + 2048 + t * 8);
        gload_lds16(bg,            Bs + t * 8);
        gload_lds16(bg + 64 * ldb, Bs + 2048 + t * 8);
        ag += 32; bg += 32;
        __syncthreads();   // compiler drains vmcnt(0) before barrier -> LDS valid
        short8 af[4], bf[4];
#pragma unroll
        for (int m = 0; m < 4; ++m)
            af[m] = *(const short8*)&As[(wm * 64 + m * 16 + li) * 32 + koff];
#pragma unroll
        for (int n = 0; n < 4; ++n)
            bf[n] = *(const short8*)&Bs[(wn * 64 + n * 16 + li) * 32 + koff];
#pragma unroll
        for (int m = 0; m < 4; ++m)
#pragma unroll
            for (int n = 0; n < 4; ++n)
                acc[m][n] = __builtin_amdgcn_mfma_f32_16x16x32_bf16(af[m], bf[n], acc[m][n], 0, 0, 0);
        __syncthreads();
    }

    // epilogue: C/D layout col = lane&15, row = (lane>>4)*4 + reg
#pragma unroll
    for (int m = 0; m < 4; ++m) {
        const int row = row0 + wm * 64 + m * 16 + (lane >> 4) * 4;
#pragma unroll
        for (int n = 0; n < 4; ++n) {
            const int col = col0 + wn * 64 + n * 16 + li;
#pragma unroll
            for (int r = 0; r < 4; ++r) {
                if (EPI == 0) {
                    ((unsigned short*)Cout)[(size_t)(row + r) * ldc + col] = f2bf(acc[m][n][r]);
                } else {
                    ((float*)Cout)[(size_t)(row + r) * ldc + col] = acc[m][n][r] + bias[col];
                }
            }
        }
    }
}

// ---------- transpose V: qkv_b[(b*N+m)*2304 + 1536 + h*64 + d] -> vt[(bh*64+d)*1024 + m] ----------
__global__ __launch_bounds__(256, 4) void transpose_v(
    const unsigned short* __restrict__ qkvb, unsigned short* __restrict__ vt)
{
    __shared__ unsigned short tile[64][65];
    const int t = threadIdx.x;
    const int bh = blockIdx.y;
    const int b = bh / NH, h = bh % NH;
    const int m0 = blockIdx.x * 64;
#pragma unroll
    for (int i = 0; i < 2; ++i) {
        int lin = i * 256 + t;            // 0..511
        int mr = lin >> 3;                // 0..63
        int dr = (lin & 7) * 8;
        short8 v = *(const short8*)(qkvb + (size_t)(b * NN + m0 + mr) * TC + 1536 + h * 64 + dr);
#pragma unroll
        for (int j = 0; j < 8; ++j) tile[mr][dr + j] = (unsigned short)v[j];
    }
    __syncthreads();
#pragma unroll
    for (int i = 0; i < 2; ++i) {
        int lin = i * 256 + t;
        int dw = lin >> 3;                // 0..63
        int mw = (lin & 7) * 8;
        short8 v;
#pragma unroll
        for (int j = 0; j < 8; ++j) v[j] = (short)tile[mw + j][dw];
        *(short8*)(vt + ((size_t)bh * 64 + dw) * NN + m0 + mw) = v;
    }
}

// ---------- fused attention ----------
// grid (N/16, B*H); block 256 = 4 waves. Wave w covers key cols [w*256, w*256+256).
// attn[n,m] = p*w[m]/sum(p*w),  p = exp(s - rowmax),  s = (q.k)*scale + mask.
__global__ __launch_bounds__(256, 2) void attn_kernel(
    const unsigned short* __restrict__ qkvb, const unsigned short* __restrict__ vt,
    const float* __restrict__ mask, const float* __restrict__ weight,
    float* __restrict__ attn_out, unsigned short* __restrict__ outb)
{
    __shared__ unsigned short P[16][1032];   // bf16 attn row-tile, XOR-swizzled cols, padded stride
    __shared__ float red_max[4][16];
    __shared__ float red_sum[4][16];

    const int t = threadIdx.x;
    const int lane = t & 63;
    const int wv = t >> 6;
    const int li = lane & 15;
    const int g = lane >> 4;
    const int koff = g * 8;
    const int bh = blockIdx.y;
    const int b = bh / NH, h = bh % NH;
    const int n0 = blockIdx.x * 16;
    const int cb = wv * 256;

    // ---- q fragments (A-operand): row = li, k(d) = koff + j (+32 for second k-step)
    const unsigned short* qp = qkvb + (size_t)(b * NN + n0 + li) * TC + h * 64 + koff;
    short8 qf0 = *(const short8*)qp;
    short8 qf1 = *(const short8*)(qp + 32);

    // ---- S = q k^T over this wave's 256 cols (16 col-frags)
    f32x4 acc[16];
#pragma unroll
    for (int cf = 0; cf < 16; ++cf) {
        const int m = cb + cf * 16 + li;
        const unsigned short* kp = qkvb + (size_t)(b * NN + m) * TC + 768 + h * 64 + koff;
        short8 k0 = *(const short8*)kp;
        short8 k1 = *(const short8*)(kp + 32);
        f32x4 c = {};
        c = __builtin_amdgcn_mfma_f32_16x16x32_bf16(qf0, k0, c, 0, 0, 0);
        c = __builtin_amdgcn_mfma_f32_16x16x32_bf16(qf1, k1, c, 0, 0, 0);
        acc[cf] = c;
    }

    // ---- scale + mask, collect weight cols, row max
    const float scale = 1.0f / 96.0f;
    float wcol[16];
    float rmax[4] = {-1e30f, -1e30f, -1e30f, -1e30f};
#pragma unroll
    for (int cf = 0; cf < 16; ++cf) {
        const int m = cb + cf * 16 + li;
        wcol[cf] = weight[b * NN + m] + 1e-10f;
        const float* mrow = mask + (size_t)b * (NN * NN) + (size_t)(n0 + g * 4) * NN + m;
#pragma unroll
        for (int r = 0; r < 4; ++r) {
            float s = acc[cf][r] * scale + mrow[r * NN];
            acc[cf][r] = s;
            rmax[r] = fmaxf(rmax[r], s);
        }
    }
#pragma unroll
    for (int d = 1; d < 16; d <<= 1)
#pragma unroll
        for (int r = 0; r < 4; ++r)
            rmax[r] = fmaxf(rmax[r], __shfl_xor(rmax[r], d, 64));
    if (li == 0) {
#pragma unroll
        for (int r = 0; r < 4; ++r) red_max[wv][g * 4 + r] = rmax[r];
    }
    __syncthreads();
#pragma unroll
    for (int r = 0; r < 4; ++r) {
        float m01 = fmaxf(red_max[0][g * 4 + r], red_max[1][g * 4 + r]);
        float m23 = fmaxf(red_max[2][g * 4 + r], red_max[3][g * 4 + r]);
        rmax[r] = fmaxf(m01, m23);
    }

    // ---- p = exp(s-max)*w, weighted row sum
    float rsum[4] = {0.f, 0.f, 0.f, 0.f};
#pragma unroll
    for (int cf = 0; cf < 16; ++cf) {
#pragma unroll
        for (int r = 0; r < 4; ++r) {
            float p = __expf(acc[cf][r] - rmax[r]) * wcol[cf];
            acc[cf][r] = p;
            rsum[r] += p;
        }
    }
#pragma unroll
    for (int d = 1; d < 16; d <<= 1)
#pragma unroll
        for (int r = 0; r < 4; ++r)
            rsum[r] += __shfl_xor(rsum[r], d, 64);
    if (li == 0) {
#pragma unroll
        for (int r = 0; r < 4; ++r) red_sum[wv][g * 4 + r] = rsum[r];
    }
    __syncthreads();
    float rinv[4];
#pragma unroll
    for (int r = 0; r < 4; ++r) {
        float s = red_sum[0][g * 4 + r] + red_sum[1][g * 4 + r]
                + red_sum[2][g * 4 + r] + red_sum[3][g * 4 + r];
        rinv[r] = 1.0f / s;
    }

    // ---- write attn (f32) + stage bf16 into LDS (XOR swizzle on 8-elem chunks)
#pragma unroll
    for (int cf = 0; cf < 16; ++cf) {
        const int m = cb + cf * 16 + li;
#pragma unroll
        for (int r = 0; r < 4; ++r) {
            const int rl = g * 4 + r;
            float a = acc[cf][r] * rinv[r];
            attn_out[(size_t)bh * (NN * NN) + (size_t)(n0 + rl) * NN + m] = a;
            P[rl][m ^ ((rl & 7) << 3)] = f2bf(a);
        }
    }
    __syncthreads();

    // ---- PV: out(16 x 64), wave handles 16 d-cols; A = P (row=li, k contiguous), B = vt
    f32x4 o = {};
    const unsigned short* vp = vt + ((size_t)bh * 64 + wv * 16 + li) * NN + koff;
#pragma unroll
    for (int kt = 0; kt < 32; ++kt) {
        short8 pa = *(const short8*)&P[li][(kt * 32 + koff) ^ ((li & 7) << 3)];
        short8 vb = *(const short8*)(vp + kt * 32);
        o = __builtin_amdgcn_mfma_f32_16x16x32_bf16(pa, vb, o, 0, 0, 0);
    }
    const int dcol = h * 64 + wv * 16 + li;
#pragma unroll
    for (int r = 0; r < 4; ++r) {
        const int row = n0 + g * 4 + r;
        outb[(size_t)(b * NN + row) * NC + dcol] = f2bf(o[r]);
    }
}

// ---------- launch ----------
extern "C" void kernel_launch(void* const* d_in, const int* in_sizes, int n_in,
                              void* d_out, int out_size, void* d_ws, size_t ws_size,
                              hipStream_t stream) {
    const float* x      = (const float*)d_in[0];
    const float* mask   = (const float*)d_in[1];
    const float* weight = (const float*)d_in[2];
    const float* qkv_w  = (const float*)d_in[3];
    const float* mu_w   = (const float*)d_in[4];
    const float* mu_b   = (const float*)d_in[5];
    const float* ls_w   = (const float*)d_in[6];
    const float* ls_b   = (const float*)d_in[7];

    char* ws = (char*)d_ws;
    unsigned short* xb   = (unsigned short*)(ws + OFF_XB);
    unsigned short* wq   = (unsigned short*)(ws + OFF_WQ);
    unsigned short* wmu  = (unsigned short*)(ws + OFF_WMU);
    unsigned short* wls  = (unsigned short*)(ws + OFF_WLS);
    unsigned short* qkvb = (unsigned short*)(ws + OFF_QKVB);
    unsigned short* vt   = (unsigned short*)(ws + OFF_VT);
    unsigned short* outb = (unsigned short*)(ws + OFF_OUTB);

    float* out_mu   = (float*)d_out;                 // (4,1024,768)
    float* out_ls   = out_mu + 3145728;              // (4,1024,768)
    float* out_attn = out_mu + 6291456;              // (4,12,1024,1024)

    // casts (all sizes divisible by 1024)
    cast_bf16<<<3145728 / 4 / 256, 256, 0, stream>>>(x, xb, 3145728 / 4);
    cast_bf16<<<1769472 / 4 / 256, 256, 0, stream>>>(qkv_w, wq, 1769472 / 4);
    cast_bf16<<<294912 / 4 / 256, 256, 0, stream>>>(mu_w, wmu, 294912 / 4);
    cast_bf16<<<294912 / 4 / 256, 256, 0, stream>>>(ls_w, wls, 294912 / 4);

    // qkv = x @ qkv_w^T  (4096 x 2304, K=768) -> bf16
    gemm_nt<0><<<dim3(TC / 128, 4096 / 128), 256, 0, stream>>>(
        xb, wq, NC, NC, NC, qkvb, TC, nullptr);

    transpose_v<<<dim3(NN / 64, NB * NH), 256, 0, stream>>>(qkvb, vt);

    attn_kernel<<<dim3(NN / 16, NB * NH), 256, 0, stream>>>(
        qkvb, vt, mask, weight, out_attn, outb);

    // mu = out[:, :384] @ mu_w^T + mu_b ; logsigma = out[:, 384:] @ ls_w^T + ls_b
    gemm_nt<1><<<dim3(NC / 128, 4096 / 128), 256, 0, stream>>>(
        outb, wmu, 384, NC, 384, out_mu, NC, mu_b);
    gemm_nt<1><<<dim3(NC / 128, 4096 / 128), 256, 0, stream>>>(
        outb + 384, wls, 384, NC, 384, out_ls, NC, ls_b);
}